// Round 1
// baseline (5000.508 us; speedup 1.0000x reference)
//
#include <hip/hip_runtime.h>
#include <stdint.h>
#include <math.h>

typedef unsigned long long u64;
typedef unsigned int u32;

#define CC   512
#define HH   50
#define WW2  76
#define PP   3800      // HH*WW2
#define NB   8
#define NA   34200     // PP*9
#define PRE  6000
#define POST 300
#define MWORDS 96      // u64 words per mask row (94 used, padded)
#define NPAD 8192      // bitonic sort size

// ---------------- workspace layout (bytes) ----------------
// wt     : 9*512*512*4            =  9,437,184   @ 0
// feat   : 8*512*3800*4           = 62,259,200   @ 9,437,184
// boxes  : 8*34200*4*4            =  4,377,600   @ 71,696,384
// scores : 8*34200*4              =  1,094,400   @ 76,073,984
// sb     : 8*6000*4               =    192,000   @ 77,168,384
// bbs    : 8*6000*16              =    768,000   @ 77,360,384
// areas  : 8*6000*4               =    192,000   @ 78,128,384
// mask   : 8*6000*96*8            = 36,864,000   @ 78,320,384
// sortbuf: 8*8192*8               =    524,288   @ 115,184,384
// total ~115.7 MB

__device__ __forceinline__ u32 skey(float f) {
    u32 u = __float_as_uint(f);
    return (u & 0x80000000u) ? ~u : (u | 0x80000000u);
}

__device__ __forceinline__ float4 anchor_at(int p, int a) {
    const float rv[3] = {0.5f, 1.0f, 2.0f};
    const float sv[3] = {8.0f, 16.0f, 32.0f};
    int ri = a / 3, si = a % 3;
    float s16 = 16.0f * sv[si];
    float hh = s16 * sqrtf(rv[ri]);
    float ww = s16 * sqrtf(1.0f / rv[ri]);
    float bx1 = 8.0f - 0.5f * ww, by1 = 8.0f - 0.5f * hh;
    float bx2 = 8.0f + 0.5f * ww, by2 = 8.0f + 0.5f * hh;
    float sx = (float)((p % WW2) * 16);
    float sy = (float)((p / WW2) * 16);
    return make_float4(sx + bx1, sy + by1, sx + bx2, sy + by2);
}

// ---------------- kernel: transpose conv1 weights to [idx9][ci][co] ----------------
__global__ void k_wt(const float* __restrict__ w, float* __restrict__ wt) {
    int t = blockIdx.x * 256 + threadIdx.x;
    if (t >= 9 * CC * CC) return;
    int co = t & 511, ci = (t >> 9) & 511, idx = t >> 18;
    wt[t] = w[((size_t)co * CC + ci) * 9 + idx];
}

// ---------------- kernel: anchors output ----------------
__global__ void k_anch(float* __restrict__ out3) {
    int t = blockIdx.x * 256 + threadIdx.x;
    if (t >= NA) return;
    int a = t % 9, p = t / 9;
    float4 an = anchor_at(p, a);
    ((float4*)out3)[t] = an;
}

// ---------------- kernel: 3x3 conv 512->512 + bias + relu (implicit GEMM) ----------
// grid (30, 4, 8), block 256.  BM=BN=128, BK=16, 8x8 microkernel.
__global__ __launch_bounds__(256) void k_conv(
    const float* __restrict__ x, const float* __restrict__ wt,
    const float* __restrict__ bias, float* __restrict__ feat)
{
    int mt = blockIdx.x, nt = blockIdx.y, img = blockIdx.z;
    int tid = threadIdx.x;
    __shared__ float As[16][132];
    __shared__ float Bs[16][128];
    int m0 = mt * 128, n0 = nt * 128;
    int lp = tid & 127;
    int lk = (tid >> 7) * 8;
    int p = m0 + lp;
    int px = p % 76, py = p / 76;
    const float* xim = x + (size_t)img * CC * PP;
    int rt = tid & 15, ct = tid >> 4;

    float acc[8][8];
#pragma unroll
    for (int i = 0; i < 8; ++i)
#pragma unroll
        for (int j = 0; j < 8; ++j) acc[i][j] = 0.f;

    for (int idx = 0; idx < 9; ++idx) {
        int dy = idx / 3 - 1, dx = idx % 3 - 1;
        bool av = (p < PP) && ((unsigned)(py + dy) < 50u) && ((unsigned)(px + dx) < 76u);
        const float* ap = xim + (p + dy * 76 + dx);
        const float* bp = wt + (size_t)idx * 512 * 512 + n0 + lp;
        for (int c0 = 0; c0 < 512; c0 += 16) {
            __syncthreads();
#pragma unroll
            for (int i = 0; i < 8; ++i) {
                int k = lk + i;
                As[k][lp] = av ? ap[(size_t)(c0 + k) * PP] : 0.f;
                Bs[k][lp] = bp[(size_t)(c0 + k) * 512];
            }
            __syncthreads();
#pragma unroll
            for (int k = 0; k < 16; ++k) {
                float4 a0 = *(const float4*)&As[k][4 * rt];
                float4 a1 = *(const float4*)&As[k][64 + 4 * rt];
                float4 b0 = *(const float4*)&Bs[k][4 * ct];
                float4 b1 = *(const float4*)&Bs[k][64 + 4 * ct];
                float a8[8] = {a0.x, a0.y, a0.z, a0.w, a1.x, a1.y, a1.z, a1.w};
                float b8[8] = {b0.x, b0.y, b0.z, b0.w, b1.x, b1.y, b1.z, b1.w};
#pragma unroll
                for (int i = 0; i < 8; ++i)
#pragma unroll
                    for (int j = 0; j < 8; ++j)
                        acc[i][j] = fmaf(a8[i], b8[j], acc[i][j]);
            }
        }
    }
    // epilogue: bias + relu, vectorized rows (rows are 4-aligned; PP%4==0)
#pragma unroll
    for (int ig = 0; ig < 2; ++ig) {
        int rowb = ig * 64 + 4 * rt;
        int pp2 = m0 + rowb;
        if (pp2 >= PP) continue;
#pragma unroll
        for (int j = 0; j < 8; ++j) {
            int co = n0 + (j >> 2) * 64 + 4 * ct + (j & 3);
            float bsv = bias[co];
            float4 v;
            v.x = fmaxf(acc[ig * 4 + 0][j] + bsv, 0.f);
            v.y = fmaxf(acc[ig * 4 + 1][j] + bsv, 0.f);
            v.z = fmaxf(acc[ig * 4 + 2][j] + bsv, 0.f);
            v.w = fmaxf(acc[ig * 4 + 3][j] + bsv, 0.f);
            *(float4*)&feat[(size_t)img * CC * PP + (size_t)co * PP + pp2] = v;
        }
    }
}

// ---------------- kernel: fused 1x1 heads + softmax + bbox decode ----------------
// grid (60, 8), block 256. Each block: 64 spatial positions.
__global__ __launch_bounds__(256) void k_heads(
    const float* __restrict__ feat,
    const float* __restrict__ lw, const float* __restrict__ lb,
    const float* __restrict__ sw, const float* __restrict__ sbias,
    const int* __restrict__ imh_p, const int* __restrict__ imw_p,
    float* __restrict__ out0, float* __restrict__ out1,
    float* __restrict__ boxes, float* __restrict__ scores)
{
    int img = blockIdx.y;
    int p0 = blockIdx.x * 64;
    int tid = threadIdx.x;
    int pl = tid & 63, cg = tid >> 6;
    __shared__ float Fs[32][65];
    __shared__ float Wsh[54][32];
    __shared__ float O[54][64];
    float acc[14];
#pragma unroll
    for (int j = 0; j < 14; ++j) acc[j] = 0.f;
    const float* fimg = feat + (size_t)img * CC * PP;

    for (int c0 = 0; c0 < CC; c0 += 32) {
        __syncthreads();
#pragma unroll
        for (int i = 0; i < 8; ++i) {
            int k = cg * 8 + i;
            int p = p0 + pl;
            Fs[k][pl] = (p < PP) ? fimg[(size_t)(c0 + k) * PP + p] : 0.f;
        }
        for (int e = tid; e < 54 * 32; e += 256) {
            int c = e >> 5, k = e & 31;
            Wsh[c][k] = (c < 36) ? lw[c * CC + c0 + k] : sw[(c - 36) * CC + c0 + k];
        }
        __syncthreads();
#pragma unroll
        for (int k = 0; k < 32; ++k) {
            float f = Fs[k][pl];
#pragma unroll
            for (int j = 0; j < 14; ++j) {
                int c = cg * 14 + j;
                if (c < 54) acc[j] = fmaf(Wsh[c][k], f, acc[j]);
            }
        }
    }
    __syncthreads();
#pragma unroll
    for (int j = 0; j < 14; ++j) {
        int c = cg * 14 + j;
        if (c < 54) O[c][pl] = acc[j] + (c < 36 ? lb[c] : sbias[c - 36]);
    }
    __syncthreads();

    float fimh = (float)(*imh_p), fimw = (float)(*imw_p);
    for (int e = tid; e < 576; e += 256) {
        int pl2 = e / 9, a = e % 9;
        int p = p0 + pl2;
        if (p >= PP) continue;
        float l0 = O[a * 4 + 0][pl2], l1 = O[a * 4 + 1][pl2];
        float l2v = O[a * 4 + 2][pl2], l3 = O[a * 4 + 3][pl2];
        float s0 = O[36 + a * 2][pl2], s1 = O[36 + a * 2 + 1][pl2];
        size_t ai = (size_t)img * NA + (size_t)p * 9 + a;
        // raw outputs
        *(float4*)&out0[ai * 4] = make_float4(l0, l1, l2v, l3);
        *(float2*)&out1[ai * 2] = make_float2(s0, s1);
        // softmax fg (2-class, max-sub like jax.nn.softmax)
        float mx = fmaxf(s0, s1);
        float e0 = expf(s0 - mx), e1 = expf(s1 - mx);
        float fg = e1 / (e0 + e1);
        // anchor + loc2bbox + clip + min-size
        float4 an = anchor_at(p, a);
        float aw = an.z - an.x, ah = an.w - an.y;
        float ax = an.x + 0.5f * aw, ay = an.y + 0.5f * ah;
        float cx = l0 * aw + ax;
        float cy = l1 * ah + ay;
        float wb = expf(l2v) * aw, hb = expf(l3) * ah;
        float x1 = cx - 0.5f * wb, y1 = cy - 0.5f * hb;
        float x2 = cx + 0.5f * wb, y2 = cy + 0.5f * hb;
        x1 = fminf(fmaxf(x1, 0.f), fimw);
        x2 = fminf(fmaxf(x2, 0.f), fimw);
        y1 = fminf(fmaxf(y1, 0.f), fimh);
        y2 = fminf(fmaxf(y2, 0.f), fimh);
        bool valid = ((x2 - x1) >= 16.0f) && ((y2 - y1) >= 16.0f);
        ((float4*)boxes)[ai] = make_float4(x1, y1, x2, y2);
        scores[ai] = valid ? fg : -INFINITY;
    }
}

// ---------------- kernel: per-image top-6000 select + stable sort ----------------
// grid 8, block 1024. Radix-threshold (4x8-bit) then global-memory bitonic sort.
__global__ __launch_bounds__(1024) void k_select(
    const float* __restrict__ scores, const float4* __restrict__ boxes,
    float* __restrict__ sb, float4* __restrict__ bbs, float* __restrict__ areas,
    u64* __restrict__ sortbuf)
{
    int img = blockIdx.x;
    int tid = threadIdx.x;
    const float* sc = scores + (size_t)img * NA;
    u64* arr = sortbuf + (size_t)img * NPAD;
    __shared__ u32 hist[256];
    __shared__ u32 s_pref, s_rem, s_cnt;
    if (tid == 0) { s_pref = 0; s_rem = PRE; }
    u32 pmask = 0;
    for (int sh = 24; sh >= 0; sh -= 8) {
        for (int i = tid; i < 256; i += 1024) hist[i] = 0;
        __syncthreads();
        u32 pref = s_pref;
        for (int e = tid; e < NA; e += 1024) {
            u32 k = skey(sc[e]);
            if ((k & pmask) == pref) atomicAdd(&hist[(k >> sh) & 255], 1);
        }
        __syncthreads();
        if (tid == 0) {
            u32 c = 0; u32 rem = s_rem; u32 pv = s_pref;
            for (int d = 255; d >= 0; --d) {
                u32 h = hist[d];
                if (c + h >= rem) { s_pref = pv | ((u32)d << sh); s_rem = rem - c; break; }
                c += h;
            }
        }
        __syncthreads();   // protect hist until tid0's scan is done
        pmask |= (0xFFu << sh);
    }
    u32 T = s_pref;
    if (tid == 0) s_cnt = 0;
    __syncthreads();
    for (int e = tid; e < NA; e += 1024) {
        u32 k = skey(sc[e]);
        if (k >= T) {
            u32 pos = atomicAdd(&s_cnt, 1);
            if (pos < NPAD) arr[pos] = ((u64)k << 32) | (u64)(~(u32)e);
        }
    }
    __syncthreads();
    u32 n = s_cnt; if (n > NPAD) n = NPAD;
    for (u32 t2 = n + tid; t2 < NPAD; t2 += 1024) arr[t2] = 0;
    // bitonic sort descending by (key, ~idx)
    for (u32 size = 2; size <= NPAD; size <<= 1) {
        for (u32 stride = size >> 1; stride > 0; stride >>= 1) {
            __syncthreads();
            for (u32 t2 = tid; t2 < NPAD / 2; t2 += 1024) {
                u32 i = 2 * t2 - (t2 & (stride - 1));
                u32 j = i + stride;
                u64 a = arr[i], b = arr[j];
                bool desc = ((i & size) == 0);
                if (desc ? (a < b) : (a > b)) { arr[i] = b; arr[j] = a; }
            }
        }
    }
    __syncthreads();
    for (int t2 = tid; t2 < PRE; t2 += 1024) {
        u64 v = arr[t2];
        u32 e = ~(u32)v;
        float s = sc[e];
        float4 bx = boxes[(size_t)img * NA + e];
        sb[img * PRE + t2] = s;
        bbs[img * PRE + t2] = bx;
        areas[img * PRE + t2] = (bx.z - bx.x) * (bx.w - bx.y);
    }
}

// ---------------- kernel: IoU suppression bitmask ----------------
// grid (94, 24, 8), block 256 = 64 i x 4 j-words. LDS-staged j boxes.
__global__ __launch_bounds__(256) void k_mask(
    const float4* __restrict__ bbs, const float* __restrict__ areas,
    u64* __restrict__ mask)
{
    int img = blockIdx.z, iT = blockIdx.x, jT = blockIdx.y;
    int tid = threadIdx.x;
    __shared__ float4 jb[256];
    __shared__ float ja[256];
    int jj = jT * 256 + tid;
    jb[tid] = (jj < PRE) ? bbs[(size_t)img * PRE + jj] : make_float4(0, 0, 0, 0);
    ja[tid] = (jj < PRE) ? areas[img * PRE + jj] : 0.f;
    __syncthreads();
    int i = iT * 64 + (tid & 63);
    int jw = jT * 4 + (tid >> 6);
    if (i >= PRE) return;
    float4 bi = bbs[(size_t)img * PRE + i];
    float ai = areas[img * PRE + i];
    int j0 = (tid >> 6) * 64;
    u64 m = 0;
#pragma unroll 4
    for (int b = 0; b < 64; ++b) {
        int j = jw * 64 + b;
        if (j >= PRE) break;
        if (j > i) {
            float4 bj = jb[j0 + b];
            float xx1 = fmaxf(bi.x, bj.x), yy1 = fmaxf(bi.y, bj.y);
            float xx2 = fminf(bi.z, bj.z), yy2 = fminf(bi.w, bj.w);
            float iw = fmaxf(xx2 - xx1, 0.f), ih2 = fmaxf(yy2 - yy1, 0.f);
            float inter = iw * ih2;
            float iou = inter / (ai + ja[j0 + b] - inter + 1e-9f);
            if (iou > 0.7f) m |= (1ull << b);
        }
    }
    mask[((size_t)img * PRE + i) * MWORDS + jw] = m;
}

// ---------------- kernel: sequential NMS scan + top-300 emit ----------------
// grid 8, block 64 (single wave).
__global__ __launch_bounds__(64) void k_scan(
    const float* __restrict__ sb, const float4* __restrict__ bbs,
    const u64* __restrict__ mask, float* __restrict__ out2)
{
    int img = blockIdx.x;
    int lane = threadIdx.x;
    __shared__ u64 keep[96];
    __shared__ int list[POST];
    __shared__ int s_n;
    for (int w = lane; w < 96; w += 64) {
        u64 bits = 0;
        for (int b = 0; b < 64; ++b) {
            int j = w * 64 + b;
            if (j < PRE) {
                float s = sb[img * PRE + j];
                if (isfinite(s)) bits |= (1ull << b);
            }
        }
        keep[w] = bits;
    }
    __syncthreads();
    for (int w = 0; w < 94; ++w) {
        u64 cur = keep[w];
        while (cur) {
            int b = __builtin_ctzll(cur);
            int i = w * 64 + b;
            const u64* mrow = mask + ((size_t)img * PRE + i) * MWORDS;
            for (int ww = lane; ww < 94; ww += 64) keep[ww] &= ~mrow[ww];
            __syncthreads();
            u64 kw = keep[w];
            cur = (b >= 63) ? 0ull : ((kw >> (b + 1)) << (b + 1));
        }
    }
    __syncthreads();
    if (lane == 0) {
        int n = 0;
        for (int w = 0; w < 94 && n < POST; ++w) {
            u64 bits = keep[w];
            while (bits && n < POST) {
                int b = __builtin_ctzll(bits);
                bits &= bits - 1;
                list[n++] = w * 64 + b;
            }
        }
        s_n = n;
    }
    __syncthreads();
    int n = s_n;
    for (int e = lane; e < POST; e += 64) {
        float4 bx = (e < n) ? bbs[(size_t)img * PRE + list[e]] : make_float4(0, 0, 0, 0);
        *(float4*)&out2[((size_t)img * POST + e) * 4] = bx;
    }
}

extern "C" void kernel_launch(void* const* d_in, const int* in_sizes, int n_in,
                              void* d_out, int out_size, void* d_ws, size_t ws_size,
                              hipStream_t stream)
{
    const float* x     = (const float*)d_in[0];
    const float* w1    = (const float*)d_in[1];
    const float* b1    = (const float*)d_in[2];
    const float* sw    = (const float*)d_in[3];
    const float* sbias = (const float*)d_in[4];
    const float* lw    = (const float*)d_in[5];
    const float* lb    = (const float*)d_in[6];
    const int*   imh   = (const int*)d_in[7];
    const int*   imw   = (const int*)d_in[8];
    float* out = (float*)d_out;
    char* ws = (char*)d_ws;

    float* wtW     = (float*)(ws + 0);
    float* featW   = (float*)(ws + 9437184);
    float* boxesW  = (float*)(ws + 71696384);
    float* scoresW = (float*)(ws + 76073984);
    float* sbW     = (float*)(ws + 77168384);
    float* bbsW    = (float*)(ws + 77360384);
    float* areasW  = (float*)(ws + 78128384);
    u64*   maskW   = (u64*)(ws + 78320384);
    u64*   sortW   = (u64*)(ws + 115184384);

    float* out0 = out;            // rpn_locs   (8,34200,4)
    float* out1 = out + 1094400;  // rpn_scores (8,34200,2)
    float* out2 = out + 1641600;  // rois       (2400,4)
    float* out3 = out + 1651200;  // anchors    (34200,4)

    hipLaunchKernelGGL(k_wt, dim3((9 * CC * CC + 255) / 256), dim3(256), 0, stream, w1, wtW);
    hipLaunchKernelGGL(k_anch, dim3((NA + 255) / 256), dim3(256), 0, stream, out3);
    hipLaunchKernelGGL(k_conv, dim3(30, 4, NB), dim3(256), 0, stream, x, wtW, b1, featW);
    hipLaunchKernelGGL(k_heads, dim3(60, NB), dim3(256), 0, stream,
                       featW, lw, lb, sw, sbias, imh, imw, out0, out1, boxesW, scoresW);
    hipLaunchKernelGGL(k_select, dim3(NB), dim3(1024), 0, stream,
                       scoresW, (const float4*)boxesW, sbW, (float4*)bbsW, areasW, sortW);
    hipLaunchKernelGGL(k_mask, dim3(94, 24, NB), dim3(256), 0, stream,
                       (const float4*)bbsW, areasW, maskW);
    hipLaunchKernelGGL(k_scan, dim3(NB), dim3(64), 0, stream,
                       sbW, (const float4*)bbsW, maskW, out2);
}